// Round 1
// 517.194 us; speedup vs baseline: 1.0124x; 1.0124x over previous
//
#include <hip/hip_runtime.h>

#define NCONN 21
#define TPB 256          // 4 waves
#define BPB 256          // batches per block

// Output: out[(i*21 + j)*B + b] = angle(u_i, u_j); row i=0 / col j=0 are 0.
//
// Phase 1: coalesced float4 global reads, scatter-stage into LDS rows of 64 floats
//          with per-row rotation of (row>>2) floats (bank-conflict-free phase 3).
// Phase 2: thread t normalizes batch t's vectors in place (own row only).
// Phase 3: wave w handles pair (i, jc+w); lane l handles batches 4l..4l+3 and
//          stores one float4 -> 1KB contiguous per wave-instruction per stream
//          (vs 256B before: this is the write-granularity fix).
__global__ __launch_bounds__(TPB, 2) void pv_kernel(const float* __restrict__ in,
                                                    float* __restrict__ out,
                                                    int B) {
    __shared__ float lds[BPB * 64];   // 64 KiB -> 2 blocks/CU
    const int tid = threadIdx.x;
    const long long blockBatch = (long long)blockIdx.x * BPB;

    // ---- Phase 1: staging ----
    // 256 batches * 63 floats = 16128 floats = 4032 float4 per block.
    const long long gBase4 = blockBatch * 63 / 4;           // blockIdx * 4032
    const long long totalF4 = ((long long)B * 63) >> 2;
    const float4* in4 = (const float4*)in;
    #pragma unroll
    for (int it = 0; it < 16; ++it) {
        int t4 = tid + it * TPB;                            // 0..4095
        if (t4 < (BPB * 63) / 4) {
            long long g4 = gBase4 + t4;
            if (g4 < totalF4) {
                float4 v = in4[g4];
                float vals[4] = {v.x, v.y, v.z, v.w};
                int f = 4 * t4;
                #pragma unroll
                for (int q = 0; q < 4; ++q) {
                    int f2 = f + q;
                    int r  = f2 / 63;                       // magic-mul, compile-time 63
                    int c  = f2 - r * 63;
                    lds[r * 64 + ((c + (r >> 2)) & 63)] = vals[q];
                }
            }
        }
    }
    __syncthreads();

    // ---- Phase 2: normalize v_e in place (own rotated row) ----
    if (blockBatch + tid < B) {
        float* row = lds + tid * 64;
        const int rot = tid >> 2;
        const float p0x = row[(0 + rot) & 63];
        const float p0y = row[(1 + rot) & 63];
        const float p0z = row[(2 + rot) & 63];
        #pragma unroll
        for (int e = 1; e < NCONN; ++e) {
            const int s0 = (3 * e + 0 + rot) & 63;
            const int s1 = (3 * e + 1 + rot) & 63;
            const int s2 = (3 * e + 2 + rot) & 63;
            float vx = row[s0] - p0x;
            float vy = row[s1] - p0y;
            float vz = row[s2] - p0z;
            float d  = fmaf(vx, vx, fmaf(vy, vy, vz * vz));
            float rr = rsqrtf(d);
            row[s0] = vx * rr;
            row[s1] = vy * rr;
            row[s2] = vz * rr;
        }
    }
    __syncthreads();

    // ---- Phase 3: angles, float4 stores ----
    const int l = tid & 63;                  // lane
    const int w = tid >> 6;                  // wave 0..3
    const int rowb = 4 * l;                  // lane's first LDS row
    // rot for rows rowb..rowb+3 is (rowb+k)>>2 == l for k<4.
    const long long remLL = B - blockBatch;
    const int rem = (int)(remLL < BPB ? remLL : (long long)BPB);
    const bool fullv = (rowb + 4 <= rem);
    float* op = out + blockBatch + rowb;     // lane's batch base
    const size_t sB = (size_t)B;

    // Zero streams: i=0 row (p=0..20) and j=0 col (p=21,42,...,420): 41 pairs.
    {
        const float4 z4 = make_float4(0.f, 0.f, 0.f, 0.f);
        for (int idx = w; idx < 41; idx += 4) {
            const int p = (idx < 21) ? idx : (idx - 20) * NCONN;
            float* dst = op + (size_t)p * sB;
            if (fullv) {
                *(float4*)dst = z4;
            } else {
                for (int k = 0; rowb + k < rem; ++k) dst[k] = 0.0f;
            }
        }
    }

    for (int i = 1; i < NCONN; ++i) {
        float uix[4], uiy[4], uiz[4];
        #pragma unroll
        for (int k = 0; k < 4; ++k) {
            const float* row = lds + (rowb + k) * 64;
            uix[k] = row[(3 * i + 0 + l) & 63];
            uiy[k] = row[(3 * i + 1 + l) & 63];
            uiz[k] = row[(3 * i + 2 + l) & 63];
        }
        const size_t pibase = (size_t)(i * NCONN) * sB;
        for (int jc = 1; jc <= 17; jc += 4) {
            const int j = jc + w;
            float ang[4];
            #pragma unroll
            for (int k = 0; k < 4; ++k) {
                const float* row = lds + (rowb + k) * 64;
                const float ujx = row[(3 * j + 0 + l) & 63];
                const float ujy = row[(3 * j + 1 + l) & 63];
                const float ujz = row[(3 * j + 2 + l) & 63];
                float c = fmaf(uix[k], ujx, fmaf(uiy[k], ujy, uiz[k] * ujz));
                // clamp; fminf first so NaN -> 1 -> acos = 0 (matches ref NaN->0)
                c = fmaxf(fminf(c, 1.0f), -1.0f);
                float t = fabsf(c);
                float s = sqrtf(1.0f - t);
                // Abramowitz & Stegun 4.4.45, |err| <= 6.7e-5
                float p = fmaf(t, -0.0187293f, 0.0742610f);
                p = fmaf(t, p, -0.2121144f);
                p = fmaf(t, p, 1.5707288f);
                float rr = s * p;
                ang[k] = (c >= 0.0f) ? rr : (3.14159265358979f - rr);
            }
            float* dst = op + pibase + (size_t)j * sB;
            if (fullv) {
                *(float4*)dst = make_float4(ang[0], ang[1], ang[2], ang[3]);
            } else {
                for (int k = 0; rowb + k < rem; ++k) dst[k] = ang[k];
            }
        }
    }
}

extern "C" void kernel_launch(void* const* d_in, const int* in_sizes, int n_in,
                              void* d_out, int out_size, void* d_ws, size_t ws_size,
                              hipStream_t stream) {
    const float* in = (const float*)d_in[0];
    float* out = (float*)d_out;
    const int B = in_sizes[0] / (NCONN * 3);   // 262144
    const int grid = (B + BPB - 1) / BPB;
    hipLaunchKernelGGL(pv_kernel, dim3(grid), dim3(TPB), 0, stream, in, out, B);
}

// Round 2
// 508.219 us; speedup vs baseline: 1.0302x; 1.0177x over previous
//
#include <hip/hip_runtime.h>

#define NCONN 21
#define TPB 512          // 8 waves
#define BPB 256          // batches per block

typedef float f4 __attribute__((ext_vector_type(4)));

// Output: out[(i*21 + j)*B + b] = angle(u_i, u_j); row i=0 / col j=0 are 0.
//
// Phase 1: coalesced float4 global reads, scatter-stage into LDS rows of 64 floats
//          with per-row rotation of (row>>2) floats (phase-3 reads 2-way = free).
// Phase 2: threads 0..255 normalize batch rows in place.
// Phase 3: 8 waves split the 400 (i,j) pairs 50 each; lane l owns batches 4l..4l+3,
//          one NON-TEMPORAL float4 store per (i,j) = 1KB/wave-instruction, bypassing
//          L2 (441 streams at 1MB stride alias L2 sets -> dirty-line shredding).
__global__ __launch_bounds__(TPB, 4) void pv_kernel(const float* __restrict__ in,
                                                    float* __restrict__ out,
                                                    int B) {
    __shared__ float lds[BPB * 64];   // 64 KiB -> 2 blocks/CU (16 waves)
    const int tid = threadIdx.x;

    // Bijective XCD-aware swizzle (grid % 8 == 0): co-resident same-XCD blocks
    // cover contiguous batch ranges -> adjacent 1KB chunks per stream.
    const int nwg = gridDim.x;
    int bid = blockIdx.x;
    if ((nwg & 7) == 0) {
        const int cpx = nwg >> 3;
        bid = (bid & 7) * cpx + (bid >> 3);
    }
    const long long blockBatch = (long long)bid * BPB;

    // ---- Phase 1: staging ----
    // 256 batches * 63 floats = 16128 floats = 4032 float4 per block.
    const long long gBase4 = blockBatch * 63 / 4;
    const long long totalF4 = ((long long)B * 63) >> 2;
    const float4* in4 = (const float4*)in;
    #pragma unroll
    for (int it = 0; it < 8; ++it) {
        int t4 = tid + it * TPB;                            // 0..4095
        if (t4 < (BPB * 63) / 4) {
            long long g4 = gBase4 + t4;
            if (g4 < totalF4) {
                float4 v = in4[g4];
                float vals[4] = {v.x, v.y, v.z, v.w};
                int f = 4 * t4;
                #pragma unroll
                for (int q = 0; q < 4; ++q) {
                    int f2 = f + q;
                    int r  = f2 / 63;                       // magic-mul
                    int c  = f2 - r * 63;
                    lds[r * 64 + ((c + (r >> 2)) & 63)] = vals[q];
                }
            }
        }
    }
    __syncthreads();

    // ---- Phase 2: normalize v_e in place (threads 0..BPB-1, own rotated row) ----
    if (tid < BPB && blockBatch + tid < B) {
        float* row = lds + tid * 64;
        const int rot = tid >> 2;
        const float p0x = row[(0 + rot) & 63];
        const float p0y = row[(1 + rot) & 63];
        const float p0z = row[(2 + rot) & 63];
        #pragma unroll
        for (int e = 1; e < NCONN; ++e) {
            const int s0 = (3 * e + 0 + rot) & 63;
            const int s1 = (3 * e + 1 + rot) & 63;
            const int s2 = (3 * e + 2 + rot) & 63;
            float vx = row[s0] - p0x;
            float vy = row[s1] - p0y;
            float vz = row[s2] - p0z;
            float d  = fmaf(vx, vx, fmaf(vy, vy, vz * vz));
            float rr = rsqrtf(d);
            row[s0] = vx * rr;
            row[s1] = vy * rr;
            row[s2] = vz * rr;
        }
    }
    __syncthreads();

    // ---- Phase 3: angles, non-temporal float4 stores ----
    const int l = tid & 63;                  // lane
    const int w = tid >> 6;                  // wave 0..7
    const int rowb = 4 * l;                  // lane's first LDS row (rot == l)
    const long long remLL = B - blockBatch;
    const int rem = (int)(remLL < BPB ? remLL : (long long)BPB);
    const bool fullv = (rowb + 4 <= rem);
    float* op = out + blockBatch + rowb;     // lane's batch base
    const size_t sB = (size_t)B;

    // Zero streams: i=0 row (p=0..20) and j=0 col (p=21,42,...,420): 41 total.
    {
        const f4 z4 = {0.f, 0.f, 0.f, 0.f};
        for (int idx = w; idx < 41; idx += 8) {
            const int p = (idx < 21) ? idx : (idx - 20) * NCONN;
            float* dst = op + (size_t)p * sB;
            if (fullv) {
                __builtin_nontemporal_store(z4, (f4*)dst);
            } else {
                for (int k = 0; rowb + k < rem; ++k) dst[k] = 0.0f;
            }
        }
    }

    // 400 pairs (i=1..20, j=1..20), 50 per wave, balanced.
    for (int idx = w; idx < 400; idx += 8) {
        const int i = idx / 20 + 1;          // magic-mul
        const int j = idx - (i - 1) * 20 + 1;
        f4 ang;
        #pragma unroll
        for (int k = 0; k < 4; ++k) {
            const float* row = lds + (rowb + k) * 64;
            const float uix = row[(3 * i + 0 + l) & 63];
            const float uiy = row[(3 * i + 1 + l) & 63];
            const float uiz = row[(3 * i + 2 + l) & 63];
            const float ujx = row[(3 * j + 0 + l) & 63];
            const float ujy = row[(3 * j + 1 + l) & 63];
            const float ujz = row[(3 * j + 2 + l) & 63];
            float c = fmaf(uix, ujx, fmaf(uiy, ujy, uiz * ujz));
            // clamp; fminf first so NaN -> 1 -> acos = 0 (matches ref NaN->0)
            c = fmaxf(fminf(c, 1.0f), -1.0f);
            float t = fabsf(c);
            float s = sqrtf(1.0f - t);
            // Abramowitz & Stegun 4.4.45, |err| <= 6.7e-5
            float p = fmaf(t, -0.0187293f, 0.0742610f);
            p = fmaf(t, p, -0.2121144f);
            p = fmaf(t, p, 1.5707288f);
            float rr = s * p;
            ang[k] = (c >= 0.0f) ? rr : (3.14159265358979f - rr);
        }
        float* dst = op + (size_t)(i * NCONN + j) * sB;
        if (fullv) {
            __builtin_nontemporal_store(ang, (f4*)dst);
        } else {
            for (int k = 0; rowb + k < rem; ++k) dst[k] = ang[k];
        }
    }
}

extern "C" void kernel_launch(void* const* d_in, const int* in_sizes, int n_in,
                              void* d_out, int out_size, void* d_ws, size_t ws_size,
                              hipStream_t stream) {
    const float* in = (const float*)d_in[0];
    float* out = (float*)d_out;
    const int B = in_sizes[0] / (NCONN * 3);   // 262144
    const int grid = (B + BPB - 1) / BPB;
    hipLaunchKernelGGL(pv_kernel, dim3(grid), dim3(TPB), 0, stream, in, out, B);
}